// Round 1
// baseline (812.044 us; speedup 1.0000x reference)
//
#include <hip/hip_runtime.h>

#define D 128
#define CHUNK 512

using short8 = __attribute__((ext_vector_type(8))) short;
using f32x4  = __attribute__((ext_vector_type(4))) float;
using f32x2  = __attribute__((ext_vector_type(2))) float;

__device__ __forceinline__ unsigned short f2bf(float f){
  unsigned u = __builtin_bit_cast(unsigned, f);
  u += 0x7fffu + ((u >> 16) & 1u);           // round-to-nearest-even
  return (unsigned short)(u >> 16);
}
__device__ __forceinline__ float bflo2f(unsigned v){
  return __builtin_bit_cast(float, v << 16);
}
__device__ __forceinline__ float bfhi2f(unsigned v){
  return __builtin_bit_cast(float, v & 0xffff0000u);
}

// ---------------- degree ----------------
__global__ void k_deg(const int* __restrict__ dst, int* __restrict__ deg, int E){
  int e = blockIdx.x * 256 + threadIdx.x;
  if (e < E) atomicAdd(&deg[dst[e]], 1);
}

// ---------------- scan (3-stage) ----------------
__global__ void k_chunksum(const int* __restrict__ deg, int* __restrict__ csum, int n){
  __shared__ int s[256];
  int tid = threadIdx.x;
  int n0 = blockIdx.x * CHUNK + tid * 2;
  int v = 0;
  if (n0     < n) v += deg[n0];
  if (n0 + 1 < n) v += deg[n0 + 1];
  s[tid] = v; __syncthreads();
  for (int off = 128; off > 0; off >>= 1){
    if (tid < off) s[tid] += s[tid + off];
    __syncthreads();
  }
  if (tid == 0) csum[blockIdx.x] = s[0];
}

__global__ void k_scanchunks(int* __restrict__ csum, int nchunks){
  __shared__ int s[256];
  int tid = threadIdx.x;
  int v = (tid < nchunks) ? csum[tid] : 0;
  s[tid] = v; __syncthreads();
  for (int off = 1; off < 256; off <<= 1){
    int t = (tid >= off) ? s[tid - off] : 0;
    __syncthreads();
    s[tid] += t;
    __syncthreads();
  }
  if (tid < nchunks) csum[tid] = s[tid] - v;   // exclusive
}

__global__ void k_offsets(const int* __restrict__ deg, const int* __restrict__ csum,
                          int* __restrict__ offs, float* __restrict__ inv, int n){
  __shared__ int s[256];
  int tid = threadIdx.x;
  int n0 = blockIdx.x * CHUNK + tid * 2;
  int d0 = (n0     < n) ? deg[n0]     : 0;
  int d1 = (n0 + 1 < n) ? deg[n0 + 1] : 0;
  int pair = d0 + d1;
  s[tid] = pair; __syncthreads();
  for (int off = 1; off < 256; off <<= 1){
    int t = (tid >= off) ? s[tid - off] : 0;
    __syncthreads();
    s[tid] += t;
    __syncthreads();
  }
  int excl = s[tid] - pair + csum[blockIdx.x];
  if (n0     <= n) offs[n0]     = excl;
  if (n0 + 1 <= n) offs[n0 + 1] = excl + d0;
  if (n0     < n) inv[n0]     = rsqrtf((float)(d0 + 1));
  if (n0 + 1 < n) inv[n0 + 1] = rsqrtf((float)(d1 + 1));
}

// ---------------- CSR fill ----------------
__global__ void k_csrfill(const int* __restrict__ src, const int* __restrict__ dst,
                          const int* __restrict__ offs, int* __restrict__ cursor,
                          const float* __restrict__ inv, int* __restrict__ csrc,
                          float* __restrict__ cw, int E){
  int e = blockIdx.x * 256 + threadIdx.x;
  if (e >= E) return;
  int s = src[e], d = dst[e];
  int pos = offs[d] + atomicAdd(&cursor[d], 1);
  csrc[pos] = s;
  cw[pos] = inv[s] * inv[d];
}

// ---------------- GEMM: hw(bf16) = act(hin) @ W ----------------
// act = identity (do_norm=0) or relu(x*scale+shift) (do_norm=1)
#define WSTRIDE 136
__global__ __launch_bounds__(512)
void k_gemm(const float* __restrict__ hin, const float* __restrict__ W,
            const float* __restrict__ scale, const float* __restrict__ shift,
            int do_norm, unsigned short* __restrict__ hw, int nrows){
  __shared__ unsigned short Wt[128 * WSTRIDE];  // transposed, padded
  int tid = threadIdx.x;
  for (int i = tid; i < 128 * 128; i += 512){
    int k = i >> 7, c = i & 127;
    Wt[c * WSTRIDE + k] = f2bf(W[i]);
  }
  __syncthreads();

  int wave = tid >> 6, lane = tid & 63;
  int r0 = blockIdx.x * 128 + wave * 16;
  int row = r0 + (lane & 15);
  int kg = lane >> 4;
  int rowc = row < nrows ? row : nrows - 1;
  const float* hrow = hin + (long)rowc * D;

  short8 a[4];
#pragma unroll
  for (int kt = 0; kt < 4; ++kt){
    int k0 = kt * 32 + kg * 8;
    f32x4 v0 = *(const f32x4*)(hrow + k0);
    f32x4 v1 = *(const f32x4*)(hrow + k0 + 4);
    float v[8] = {v0[0], v0[1], v0[2], v0[3], v1[0], v1[1], v1[2], v1[3]};
    if (do_norm){
#pragma unroll
      for (int j = 0; j < 8; ++j)
        v[j] = fmaxf(0.f, v[j] * scale[k0 + j] + shift[k0 + j]);
    }
    short8 t;
#pragma unroll
    for (int j = 0; j < 8; ++j) t[j] = (short)f2bf(v[j]);
    a[kt] = t;
  }

  f32x4 acc[8] = {};
#pragma unroll
  for (int ct = 0; ct < 8; ++ct){
    int col = ct * 16 + (lane & 15);
    const unsigned short* bp = &Wt[col * WSTRIDE + kg * 8];
#pragma unroll
    for (int kt = 0; kt < 4; ++kt){
      short8 b = *(const short8*)(bp + kt * 32);
      acc[ct] = __builtin_amdgcn_mfma_f32_16x16x32_bf16(a[kt], b, acc[ct], 0, 0, 0);
    }
  }

  int colbase = lane & 15;
  int rowo = r0 + kg * 4;
#pragma unroll
  for (int ct = 0; ct < 8; ++ct){
    int col = ct * 16 + colbase;
#pragma unroll
    for (int r = 0; r < 4; ++r){
      int rr = rowo + r;
      if (rr < nrows) hw[(long)rr * D + col] = f2bf(acc[ct][r]);
    }
  }
}

// ---------------- aggregate + BN partial stats ----------------
__global__ __launch_bounds__(256)
void k_agg(const unsigned short* __restrict__ hw, const float* __restrict__ inv,
           const int* __restrict__ offs, const int* __restrict__ csrc,
           const float* __restrict__ cw, const float* __restrict__ bias,
           float* __restrict__ agg, float* __restrict__ stats, int n){
  int tid = threadIdx.x, lane = tid & 63, wv = tid >> 6;
  int gw = blockIdx.x * 4 + wv, stride = gridDim.x * 4;
  int c0 = lane * 2;
  float b0 = bias[c0], b1 = bias[c0 + 1];
  float s0 = 0, s1 = 0, q0 = 0, q1 = 0;

  for (int nd = gw; nd < n; nd += stride){
    float iv = inv[nd];
    float self = iv * iv;
    unsigned v = *(const unsigned*)(hw + (long)nd * D + c0);
    float a0 = bflo2f(v) * self + b0;
    float a1 = bfhi2f(v) * self + b1;
    int e = offs[nd], e1 = offs[nd + 1];
    for (; e + 1 < e1; e += 2){
      int sA = csrc[e], sB = csrc[e + 1];
      float wA = cw[e], wB = cw[e + 1];
      unsigned vA = *(const unsigned*)(hw + (long)sA * D + c0);
      unsigned vB = *(const unsigned*)(hw + (long)sB * D + c0);
      a0 += bflo2f(vA) * wA; a1 += bfhi2f(vA) * wA;
      a0 += bflo2f(vB) * wB; a1 += bfhi2f(vB) * wB;
    }
    if (e < e1){
      int sA = csrc[e];
      float wA = cw[e];
      unsigned vA = *(const unsigned*)(hw + (long)sA * D + c0);
      a0 += bflo2f(vA) * wA; a1 += bfhi2f(vA) * wA;
    }
    f32x2 r; r[0] = a0; r[1] = a1;
    *(f32x2*)(agg + (long)nd * D + c0) = r;
    s0 += a0; s1 += a1; q0 += a0 * a0; q1 += a1 * a1;
  }

  __shared__ float red[4][64][4];
  red[wv][lane][0] = s0; red[wv][lane][1] = s1;
  red[wv][lane][2] = q0; red[wv][lane][3] = q1;
  __syncthreads();
  if (tid < 64){
    float t0 = 0, t1 = 0, t2 = 0, t3 = 0;
#pragma unroll
    for (int w = 0; w < 4; ++w){
      t0 += red[w][tid][0]; t1 += red[w][tid][1];
      t2 += red[w][tid][2]; t3 += red[w][tid][3];
    }
    atomicAdd(&stats[2 * tid],           t0);
    atomicAdd(&stats[2 * tid + 1],       t1);
    atomicAdd(&stats[128 + 2 * tid],     t2);
    atomicAdd(&stats[128 + 2 * tid + 1], t3);
  }
}

// ---------------- BN finalize ----------------
__global__ void k_bn(const float* __restrict__ stats, const float* __restrict__ gamma,
                     const float* __restrict__ beta, float* __restrict__ scale,
                     float* __restrict__ shift, float invn){
  int c = threadIdx.x;
  float mean = stats[c] * invn;
  float var = stats[128 + c] * invn - mean * mean;
  float isd = rsqrtf(var + 1e-5f);
  float sc = gamma[c] * isd;
  scale[c] = sc;
  shift[c] = beta[c] - mean * sc;
}

// ---------------- pool (fused BN+ReLU of last layer) ----------------
__global__ __launch_bounds__(256)
void k_pool(const float* __restrict__ agg, const float* __restrict__ scale,
            const float* __restrict__ shift, const int* __restrict__ batch,
            float* __restrict__ out, int n){
  int tid = threadIdx.x, lane = tid & 63, wv = tid >> 6;
  int gw = blockIdx.x * 4 + wv;
  int n0 = gw * 64;
  if (n0 >= n) return;
  int n1 = min(n0 + 64, n);
  int c0 = lane * 2;
  float sc0 = scale[c0], sc1 = scale[c0 + 1];
  float sh0 = shift[c0], sh1 = shift[c0 + 1];
  int g = batch[n0];
  float a0 = 0, a1 = 0;
  for (int nd = n0; nd < n1; ++nd){
    int gn = batch[nd];
    if (gn != g){
      atomicAdd(&out[(long)g * D + c0],     a0);
      atomicAdd(&out[(long)g * D + c0 + 1], a1);
      a0 = 0; a1 = 0; g = gn;
    }
    f32x2 v = *(const f32x2*)(agg + (long)nd * D + c0);
    a0 += fmaxf(0.f, v[0] * sc0 + sh0);
    a1 += fmaxf(0.f, v[1] * sc1 + sh1);
  }
  atomicAdd(&out[(long)g * D + c0],     a0);
  atomicAdd(&out[(long)g * D + c0 + 1], a1);
}

extern "C" void kernel_launch(void* const* d_in, const int* in_sizes, int n_in,
                              void* d_out, int out_size, void* d_ws, size_t ws_size,
                              hipStream_t stream){
  const float* x      = (const float*)d_in[0];
  const int*   ei     = (const int*)d_in[1];
  const int*   batch  = (const int*)d_in[2];
  const float* Ws     = (const float*)d_in[3];
  const float* bs     = (const float*)d_in[4];
  const float* gammas = (const float*)d_in[5];
  const float* betas  = (const float*)d_in[6];

  const int E_ = in_sizes[1] / 2;
  const int N_ = in_sizes[2];
  const int* src = ei;
  const int* dst = ei + E_;

  char* p = (char*)d_ws;
  auto alloc = [&](size_t bytes) -> void* {
    void* r = (void*)p;
    p += (bytes + 255) & ~(size_t)255;
    return r;
  };
  float*          bufA   = (float*)         alloc((size_t)N_ * D * 4);
  unsigned short* hw     = (unsigned short*)alloc((size_t)N_ * D * 2);
  int*            deg    = (int*)           alloc((size_t)N_ * 4);
  float*          inv    = (float*)         alloc((size_t)N_ * 4);
  int*            offs   = (int*)           alloc((size_t)(N_ + 1) * 4);
  int*            cursor = (int*)           alloc((size_t)N_ * 4);
  int*            csrc   = (int*)           alloc((size_t)E_ * 4);
  float*          cwt    = (float*)         alloc((size_t)E_ * 4);
  float*          stats  = (float*)         alloc(3 * 256 * 4);
  float*          scales = (float*)         alloc(3 * 128 * 4);
  float*          shifts = (float*)         alloc(3 * 128 * 4);
  int*            csum   = (int*)           alloc(256 * 4);

  hipMemsetAsync(deg,    0, (size_t)N_ * 4, stream);
  hipMemsetAsync(cursor, 0, (size_t)N_ * 4, stream);
  hipMemsetAsync(stats,  0, 3 * 256 * 4, stream);
  hipMemsetAsync(d_out,  0, (size_t)out_size * 4, stream);

  int nchunks = (N_ + CHUNK - 1) / CHUNK;
  k_deg       <<<(E_ + 255) / 256, 256, 0, stream>>>(dst, deg, E_);
  k_chunksum  <<<nchunks, 256, 0, stream>>>(deg, csum, N_);
  k_scanchunks<<<1, 256, 0, stream>>>(csum, nchunks);
  k_offsets   <<<nchunks, 256, 0, stream>>>(deg, csum, offs, inv, N_);
  k_csrfill   <<<(E_ + 255) / 256, 256, 0, stream>>>(src, dst, offs, cursor, inv, csrc, cwt, E_);

  int gemm_blocks = (N_ + 127) / 128;
  for (int l = 0; l < 3; ++l){
    const float* hin = (l == 0) ? x : bufA;
    const float* sc  = (l == 0) ? nullptr : scales + (l - 1) * 128;
    const float* sh  = (l == 0) ? nullptr : shifts + (l - 1) * 128;
    k_gemm<<<gemm_blocks, 512, 0, stream>>>(hin, Ws + (size_t)l * D * D, sc, sh,
                                            (l == 0) ? 0 : 1, hw, N_);
    k_agg<<<1024, 256, 0, stream>>>(hw, inv, offs, csrc, cwt, bs + (size_t)l * D,
                                    bufA, stats + (size_t)l * 256, N_);
    k_bn<<<1, 128, 0, stream>>>(stats + (size_t)l * 256, gammas + (size_t)l * D,
                                betas + (size_t)l * D, scales + (size_t)l * 128,
                                shifts + (size_t)l * 128, 1.0f / (float)N_);
  }
  k_pool<<<(N_ + 255) / 256, 256, 0, stream>>>(bufA, scales + 2 * 128, shifts + 2 * 128,
                                               batch, (float*)d_out, N_);
}

// Round 2
// 738.425 us; speedup vs baseline: 1.0997x; 1.0997x over previous
//
#include <hip/hip_runtime.h>

#define D 128
#define CHUNK 512

using short8 = __attribute__((ext_vector_type(8))) short;
using f32x4  = __attribute__((ext_vector_type(4))) float;
using f32x2  = __attribute__((ext_vector_type(2))) float;

__device__ __forceinline__ unsigned short f2bf(float f){
  unsigned u = __builtin_bit_cast(unsigned, f);
  u += 0x7fffu + ((u >> 16) & 1u);           // round-to-nearest-even
  return (unsigned short)(u >> 16);
}
__device__ __forceinline__ float bflo2f(unsigned v){
  return __builtin_bit_cast(float, v << 16);
}
__device__ __forceinline__ float bfhi2f(unsigned v){
  return __builtin_bit_cast(float, v & 0xffff0000u);
}

// ---------------- degree ----------------
__global__ void k_deg(const int* __restrict__ dst, int* __restrict__ deg, int E){
  int e = blockIdx.x * 256 + threadIdx.x;
  if (e < E) atomicAdd(&deg[dst[e]], 1);
}

// ---------------- scan (3-stage) ----------------
__global__ void k_chunksum(const int* __restrict__ deg, int* __restrict__ csum, int n){
  __shared__ int s[256];
  int tid = threadIdx.x;
  int n0 = blockIdx.x * CHUNK + tid * 2;
  int v = 0;
  if (n0     < n) v += deg[n0];
  if (n0 + 1 < n) v += deg[n0 + 1];
  s[tid] = v; __syncthreads();
  for (int off = 128; off > 0; off >>= 1){
    if (tid < off) s[tid] += s[tid + off];
    __syncthreads();
  }
  if (tid == 0) csum[blockIdx.x] = s[0];
}

__global__ void k_scanchunks(int* __restrict__ csum, int nchunks){
  __shared__ int s[256];
  int tid = threadIdx.x;
  int v = (tid < nchunks) ? csum[tid] : 0;
  s[tid] = v; __syncthreads();
  for (int off = 1; off < 256; off <<= 1){
    int t = (tid >= off) ? s[tid - off] : 0;
    __syncthreads();
    s[tid] += t;
    __syncthreads();
  }
  if (tid < nchunks) csum[tid] = s[tid] - v;   // exclusive
}

__global__ void k_offsets(const int* __restrict__ deg, const int* __restrict__ csum,
                          int* __restrict__ offs, float* __restrict__ inv, int n){
  __shared__ int s[256];
  int tid = threadIdx.x;
  int n0 = blockIdx.x * CHUNK + tid * 2;
  int d0 = (n0     < n) ? deg[n0]     : 0;
  int d1 = (n0 + 1 < n) ? deg[n0 + 1] : 0;
  int pair = d0 + d1;
  s[tid] = pair; __syncthreads();
  for (int off = 1; off < 256; off <<= 1){
    int t = (tid >= off) ? s[tid - off] : 0;
    __syncthreads();
    s[tid] += t;
    __syncthreads();
  }
  int excl = s[tid] - pair + csum[blockIdx.x];
  if (n0     <= n) offs[n0]     = excl;
  if (n0 + 1 <= n) offs[n0 + 1] = excl + d0;
  if (n0     < n) inv[n0]     = rsqrtf((float)(d0 + 1));
  if (n0 + 1 < n) inv[n0 + 1] = rsqrtf((float)(d1 + 1));
}

// ---------------- CSR fill ----------------
__global__ void k_csrfill(const int* __restrict__ src, const int* __restrict__ dst,
                          const int* __restrict__ offs, int* __restrict__ cursor,
                          const float* __restrict__ inv, int* __restrict__ csrc,
                          float* __restrict__ cw, int E){
  int e = blockIdx.x * 256 + threadIdx.x;
  if (e >= E) return;
  int s = src[e], d = dst[e];
  int pos = offs[d] + atomicAdd(&cursor[d], 1);
  csrc[pos] = s;
  cw[pos] = inv[s] * inv[d];
}

// ---------------- GEMM: hw(bf16) = act(hin) @ W ----------------
// act = identity (do_norm=0) or relu(x*scale+shift) (do_norm=1)
#define WSTRIDE 136
__global__ __launch_bounds__(512)
void k_gemm(const float* __restrict__ hin, const float* __restrict__ W,
            const float* __restrict__ scale, const float* __restrict__ shift,
            int do_norm, unsigned short* __restrict__ hw, int nrows){
  __shared__ unsigned short Wt[128 * WSTRIDE];  // transposed, padded
  int tid = threadIdx.x;
  for (int i = tid; i < 128 * 128; i += 512){
    int k = i >> 7, c = i & 127;
    Wt[c * WSTRIDE + k] = f2bf(W[i]);
  }
  __syncthreads();

  int wave = tid >> 6, lane = tid & 63;
  int r0 = blockIdx.x * 128 + wave * 16;
  int row = r0 + (lane & 15);
  int kg = lane >> 4;
  int rowc = row < nrows ? row : nrows - 1;
  const float* hrow = hin + (long)rowc * D;

  short8 a[4];
#pragma unroll
  for (int kt = 0; kt < 4; ++kt){
    int k0 = kt * 32 + kg * 8;
    f32x4 v0 = *(const f32x4*)(hrow + k0);
    f32x4 v1 = *(const f32x4*)(hrow + k0 + 4);
    float v[8] = {v0[0], v0[1], v0[2], v0[3], v1[0], v1[1], v1[2], v1[3]};
    if (do_norm){
#pragma unroll
      for (int j = 0; j < 8; ++j)
        v[j] = fmaxf(0.f, v[j] * scale[k0 + j] + shift[k0 + j]);
    }
    short8 t;
#pragma unroll
    for (int j = 0; j < 8; ++j) t[j] = (short)f2bf(v[j]);
    a[kt] = t;
  }

  f32x4 acc[8] = {};
#pragma unroll
  for (int ct = 0; ct < 8; ++ct){
    int col = ct * 16 + (lane & 15);
    const unsigned short* bp = &Wt[col * WSTRIDE + kg * 8];
#pragma unroll
    for (int kt = 0; kt < 4; ++kt){
      short8 b = *(const short8*)(bp + kt * 32);
      acc[ct] = __builtin_amdgcn_mfma_f32_16x16x32_bf16(a[kt], b, acc[ct], 0, 0, 0);
    }
  }

  int colbase = lane & 15;
  int rowo = r0 + kg * 4;
#pragma unroll
  for (int ct = 0; ct < 8; ++ct){
    int col = ct * 16 + colbase;
#pragma unroll
    for (int r = 0; r < 4; ++r){
      int rr = rowo + r;
      if (rr < nrows) hw[(long)rr * D + col] = f2bf(acc[ct][r]);
    }
  }
}

// ---------------- aggregate + BN partial stats ----------------
// contiguous node chunk per wave; 4-wide edge unroll w/ independent
// accumulators + predicated tail; nontemporal agg store.
__global__ __launch_bounds__(256)
void k_agg(const unsigned short* __restrict__ hw, const float* __restrict__ inv,
           const int* __restrict__ offs, const int* __restrict__ csrc,
           const float* __restrict__ cw, const float* __restrict__ bias,
           float* __restrict__ agg, float* __restrict__ stats, int n){
  int tid = threadIdx.x, lane = tid & 63, wv = tid >> 6;
  int gw = blockIdx.x * 4 + wv;
  int nwaves = gridDim.x * 4;
  int per = (n + nwaves - 1) / nwaves;
  int n0 = gw * per, n1 = min(n0 + per, n);
  int c0 = lane * 2;
  float b0 = bias[c0], b1 = bias[c0 + 1];
  float s0 = 0, s1 = 0, q0 = 0, q1 = 0;

  for (int nd = n0; nd < n1; ++nd){
    float iv = inv[nd];
    float self = iv * iv;
    unsigned v = *(const unsigned*)(hw + (long)nd * D + c0);
    float a0 = bflo2f(v) * self + b0;
    float a1 = bfhi2f(v) * self + b1;
    float p0 = 0, p1 = 0, r0 = 0, r1 = 0, t0 = 0, t1 = 0;
    int e = offs[nd], ee = offs[nd + 1];
    for (; e + 4 <= ee; e += 4){
      int sA = csrc[e],     sB = csrc[e + 1];
      int sC = csrc[e + 2], sD = csrc[e + 3];
      float wA = cw[e],     wB = cw[e + 1];
      float wC = cw[e + 2], wD = cw[e + 3];
      unsigned vA = *(const unsigned*)(hw + (long)sA * D + c0);
      unsigned vB = *(const unsigned*)(hw + (long)sB * D + c0);
      unsigned vC = *(const unsigned*)(hw + (long)sC * D + c0);
      unsigned vD = *(const unsigned*)(hw + (long)sD * D + c0);
      a0 += bflo2f(vA) * wA; a1 += bfhi2f(vA) * wA;
      p0 += bflo2f(vB) * wB; p1 += bfhi2f(vB) * wB;
      r0 += bflo2f(vC) * wC; r1 += bfhi2f(vC) * wC;
      t0 += bflo2f(vD) * wD; t1 += bfhi2f(vD) * wD;
    }
    if (e < ee){
      int last = ee - 1;
      int i1 = min(e + 1, last), i2 = min(e + 2, last), i3 = min(e + 3, last);
      int sA = csrc[e], sB = csrc[i1], sC = csrc[i2], sD = csrc[i3];
      float wA = cw[e];
      float wB = (e + 1 < ee) ? cw[i1] : 0.f;
      float wC = (e + 2 < ee) ? cw[i2] : 0.f;
      float wD = (e + 3 < ee) ? cw[i3] : 0.f;
      unsigned vA = *(const unsigned*)(hw + (long)sA * D + c0);
      unsigned vB = *(const unsigned*)(hw + (long)sB * D + c0);
      unsigned vC = *(const unsigned*)(hw + (long)sC * D + c0);
      unsigned vD = *(const unsigned*)(hw + (long)sD * D + c0);
      a0 += bflo2f(vA) * wA; a1 += bfhi2f(vA) * wA;
      p0 += bflo2f(vB) * wB; p1 += bfhi2f(vB) * wB;
      r0 += bflo2f(vC) * wC; r1 += bfhi2f(vC) * wC;
      t0 += bflo2f(vD) * wD; t1 += bfhi2f(vD) * wD;
    }
    a0 += p0 + r0 + t0;
    a1 += p1 + r1 + t1;
    f32x2 rr; rr[0] = a0; rr[1] = a1;
    __builtin_nontemporal_store(rr, (f32x2*)(agg + (long)nd * D + c0));
    s0 += a0; s1 += a1; q0 += a0 * a0; q1 += a1 * a1;
  }

  __shared__ float red[4][64][4];
  red[wv][lane][0] = s0; red[wv][lane][1] = s1;
  red[wv][lane][2] = q0; red[wv][lane][3] = q1;
  __syncthreads();
  if (tid < 64){
    float t0 = 0, t1 = 0, t2 = 0, t3 = 0;
#pragma unroll
    for (int w = 0; w < 4; ++w){
      t0 += red[w][tid][0]; t1 += red[w][tid][1];
      t2 += red[w][tid][2]; t3 += red[w][tid][3];
    }
    atomicAdd(&stats[2 * tid],           t0);
    atomicAdd(&stats[2 * tid + 1],       t1);
    atomicAdd(&stats[128 + 2 * tid],     t2);
    atomicAdd(&stats[128 + 2 * tid + 1], t3);
  }
}

// ---------------- BN finalize ----------------
__global__ void k_bn(const float* __restrict__ stats, const float* __restrict__ gamma,
                     const float* __restrict__ beta, float* __restrict__ scale,
                     float* __restrict__ shift, float invn){
  int c = threadIdx.x;
  float mean = stats[c] * invn;
  float var = stats[128 + c] * invn - mean * mean;
  float isd = rsqrtf(var + 1e-5f);
  float sc = gamma[c] * isd;
  scale[c] = sc;
  shift[c] = beta[c] - mean * sc;
}

// ---------------- pool (fused BN+ReLU of last layer) ----------------
__global__ __launch_bounds__(256)
void k_pool(const float* __restrict__ agg, const float* __restrict__ scale,
            const float* __restrict__ shift, const int* __restrict__ batch,
            float* __restrict__ out, int n){
  int tid = threadIdx.x, lane = tid & 63, wv = tid >> 6;
  int gw = blockIdx.x * 4 + wv;
  int n0 = gw * 64;
  if (n0 >= n) return;
  int n1 = min(n0 + 64, n);
  int c0 = lane * 2;
  float sc0 = scale[c0], sc1 = scale[c0 + 1];
  float sh0 = shift[c0], sh1 = shift[c0 + 1];
  int g = batch[n0];
  float a0 = 0, a1 = 0;
  for (int nd = n0; nd < n1; ++nd){
    int gn = batch[nd];
    if (gn != g){
      atomicAdd(&out[(long)g * D + c0],     a0);
      atomicAdd(&out[(long)g * D + c0 + 1], a1);
      a0 = 0; a1 = 0; g = gn;
    }
    f32x2 v = *(const f32x2*)(agg + (long)nd * D + c0);
    a0 += fmaxf(0.f, v[0] * sc0 + sh0);
    a1 += fmaxf(0.f, v[1] * sc1 + sh1);
  }
  atomicAdd(&out[(long)g * D + c0],     a0);
  atomicAdd(&out[(long)g * D + c0 + 1], a1);
}

extern "C" void kernel_launch(void* const* d_in, const int* in_sizes, int n_in,
                              void* d_out, int out_size, void* d_ws, size_t ws_size,
                              hipStream_t stream){
  const float* x      = (const float*)d_in[0];
  const int*   ei     = (const int*)d_in[1];
  const int*   batch  = (const int*)d_in[2];
  const float* Ws     = (const float*)d_in[3];
  const float* bs     = (const float*)d_in[4];
  const float* gammas = (const float*)d_in[5];
  const float* betas  = (const float*)d_in[6];

  const int E_ = in_sizes[1] / 2;
  const int N_ = in_sizes[2];
  const int* src = ei;
  const int* dst = ei + E_;

  char* p = (char*)d_ws;
  auto alloc = [&](size_t bytes) -> void* {
    void* r = (void*)p;
    p += (bytes + 255) & ~(size_t)255;
    return r;
  };
  float*          bufA   = (float*)         alloc((size_t)N_ * D * 4);
  unsigned short* hw     = (unsigned short*)alloc((size_t)N_ * D * 2);
  int*            deg    = (int*)           alloc((size_t)N_ * 4);
  float*          inv    = (float*)         alloc((size_t)N_ * 4);
  int*            offs   = (int*)           alloc((size_t)(N_ + 1) * 4);
  int*            cursor = (int*)           alloc((size_t)N_ * 4);
  int*            csrc   = (int*)           alloc((size_t)E_ * 4);
  float*          cwt    = (float*)         alloc((size_t)E_ * 4);
  float*          stats  = (float*)         alloc(3 * 256 * 4);
  float*          scales = (float*)         alloc(3 * 128 * 4);
  float*          shifts = (float*)         alloc(3 * 128 * 4);
  int*            csum   = (int*)           alloc(256 * 4);

  hipMemsetAsync(deg,    0, (size_t)N_ * 4, stream);
  hipMemsetAsync(cursor, 0, (size_t)N_ * 4, stream);
  hipMemsetAsync(stats,  0, 3 * 256 * 4, stream);
  hipMemsetAsync(d_out,  0, (size_t)out_size * 4, stream);

  int nchunks = (N_ + CHUNK - 1) / CHUNK;
  k_deg       <<<(E_ + 255) / 256, 256, 0, stream>>>(dst, deg, E_);
  k_chunksum  <<<nchunks, 256, 0, stream>>>(deg, csum, N_);
  k_scanchunks<<<1, 256, 0, stream>>>(csum, nchunks);
  k_offsets   <<<nchunks, 256, 0, stream>>>(deg, csum, offs, inv, N_);
  k_csrfill   <<<(E_ + 255) / 256, 256, 0, stream>>>(src, dst, offs, cursor, inv, csrc, cwt, E_);

  int gemm_blocks = (N_ + 127) / 128;
  for (int l = 0; l < 3; ++l){
    const float* hin = (l == 0) ? x : bufA;
    const float* sc  = (l == 0) ? nullptr : scales + (l - 1) * 128;
    const float* sh  = (l == 0) ? nullptr : shifts + (l - 1) * 128;
    k_gemm<<<gemm_blocks, 512, 0, stream>>>(hin, Ws + (size_t)l * D * D, sc, sh,
                                            (l == 0) ? 0 : 1, hw, N_);
    k_agg<<<2048, 256, 0, stream>>>(hw, inv, offs, csrc, cwt, bs + (size_t)l * D,
                                    bufA, stats + (size_t)l * 256, N_);
    k_bn<<<1, 128, 0, stream>>>(stats + (size_t)l * 256, gammas + (size_t)l * D,
                                betas + (size_t)l * D, scales + (size_t)l * 128,
                                shifts + (size_t)l * 128, 1.0f / (float)N_);
  }
  k_pool<<<(N_ + 255) / 256, 256, 0, stream>>>(bufA, scales + 2 * 128, shifts + 2 * 128,
                                               batch, (float*)d_out, N_);
}